// Round 1
// baseline (11198.185 us; speedup 1.0000x reference)
//
#include <hip/hip_runtime.h>
#include <stdint.h>

#define B_  32
#define T_  512
#define E_  1024
#define H_  1024
#define L_  128
#define BT  (B_*T_)    // 16384
#define G3  (3*H_)     // 3072

typedef float f32x4 __attribute__((ext_vector_type(4)));
typedef short bf16x8 __attribute__((ext_vector_type(8)));

__device__ __forceinline__ unsigned short f2bf(float f) {
  unsigned u = __float_as_uint(f);
  u = (u + 0x7fffu + ((u >> 16) & 1u)) >> 16;
  return (unsigned short)u;
}
__device__ __forceinline__ float bf2f(unsigned short s) {
  return __uint_as_float(((unsigned)s) << 16);
}

// ---------------- fp32 -> bf16 convert ----------------
__global__ void k_f2bf(const float* __restrict__ in, unsigned short* __restrict__ out, int n) {
  int i = (blockIdx.x * blockDim.x + threadIdx.x) * 4;
  if (i >= n) return;
  float4 v = *(const float4*)(in + i);
  unsigned lo = (unsigned)f2bf(v.x) | ((unsigned)f2bf(v.y) << 16);
  unsigned hi = (unsigned)f2bf(v.z) | ((unsigned)f2bf(v.w) << 16);
  *(uint2*)(out + i) = make_uint2(lo, hi);
}

// ---------------- bf16 GEMM: C = act(A @ W^T + bias) ----------------
// A:[M,K] bf16 row-major, W:[N,K] bf16 row-major, bias fp32[N].
// 128x128 tile, BK=64, 4 waves (2x2), each wave 64x64 via 4x4 mfma_f32_16x16x32_bf16.
template<int OUT_F32, int RELU>
__global__ __launch_bounds__(256)
void k_gemm(const unsigned short* __restrict__ A, const unsigned short* __restrict__ W,
            const float* __restrict__ bias, void* __restrict__ Cc,
            int M, int N, int K)
{
  __shared__ __align__(16) unsigned short As[128 * 64];
  __shared__ __align__(16) unsigned short Bs[128 * 64];
  const int m0 = blockIdx.x * 128, n0 = blockIdx.y * 128;
  const int tid = threadIdx.x;
  const int lane = tid & 63, wv = tid >> 6;
  const int wr = wv >> 1, wc = wv & 1;
  f32x4 acc[4][4] = {};

  for (int k0 = 0; k0 < K; k0 += 64) {
#pragma unroll
    for (int i = 0; i < 4; ++i) {
      int o = tid * 16 + i * 4096;       // byte offset within 16KB tile
      int r = o >> 7;                    // row 0..127
      int cb = o & 127;                  // byte within row
      const unsigned short* ga = A + (size_t)(m0 + r) * K + k0 + (cb >> 1);
      const unsigned short* gb = W + (size_t)(n0 + r) * K + k0 + (cb >> 1);
      __builtin_amdgcn_global_load_lds((const __attribute__((address_space(1))) void*)ga,
          (__attribute__((address_space(3))) void*)((char*)As + o), 16, 0, 0);
      __builtin_amdgcn_global_load_lds((const __attribute__((address_space(1))) void*)gb,
          (__attribute__((address_space(3))) void*)((char*)Bs + o), 16, 0, 0);
    }
    __syncthreads();
#pragma unroll
    for (int kk = 0; kk < 2; ++kk) {
      bf16x8 af[4], bfr[4];
#pragma unroll
      for (int m = 0; m < 4; ++m)
        af[m] = *(const bf16x8*)(As + (wr * 64 + m * 16 + (lane & 15)) * 64 + kk * 32 + (lane >> 4) * 8);
#pragma unroll
      for (int n = 0; n < 4; ++n)
        bfr[n] = *(const bf16x8*)(Bs + (wc * 64 + n * 16 + (lane & 15)) * 64 + kk * 32 + (lane >> 4) * 8);
#pragma unroll
      for (int m = 0; m < 4; ++m)
#pragma unroll
        for (int n = 0; n < 4; ++n)
          acc[m][n] = __builtin_amdgcn_mfma_f32_16x16x32_bf16(af[m], bfr[n], acc[m][n], 0, 0, 0);
    }
    __syncthreads();
  }
#pragma unroll
  for (int m = 0; m < 4; ++m) {
    int row0 = m0 + wr * 64 + m * 16 + (lane >> 4) * 4;
#pragma unroll
    for (int n = 0; n < 4; ++n) {
      int col = n0 + wc * 64 + n * 16 + (lane & 15);
      float bvv = bias[col];
#pragma unroll
      for (int q = 0; q < 4; ++q) {
        float v = acc[m][n][q] + bvv;
        if (RELU) v = fmaxf(v, 0.f);
        size_t idx = (size_t)(row0 + q) * N + col;
        if (OUT_F32) ((float*)Cc)[idx] = v;
        else ((unsigned short*)Cc)[idx] = f2bf(v);
      }
    }
  }
}

// ---------------- global barrier (monotonic counter, agent scope) ----------------
__device__ __forceinline__ void gbar(unsigned* bar, unsigned target) {
  __syncthreads();
  if (threadIdx.x == 0) {
    __hip_atomic_fetch_add(bar, 1u, __ATOMIC_ACQ_REL, __HIP_MEMORY_SCOPE_AGENT);
    while (__hip_atomic_load(bar, __ATOMIC_ACQUIRE, __HIP_MEMORY_SCOPE_AGENT) < target) {
      __builtin_amdgcn_s_sleep(8);
    }
  }
  __syncthreads();
}

// ---------------- persistent GRU ----------------
// 64 WGs x 384 threads (6 waves). WG owns 16 hidden units U0=wg*16.
// Wave wv: mt=wv&1 (batch half), g=wv>>1 (gate). Whh slice resident in regs (32 bf16x8).
// h broadcast: hbuf[2][32][1024] bf16, double-buffered, per-step device barrier.
template<int IS_DEC>
__global__ __launch_bounds__(384, 2)
void k_gru(const unsigned short* __restrict__ gi,    // [B,T,3072] bf16 (includes bih)
           const unsigned short* __restrict__ Whhb,  // [3072,1024] bf16
           const float* __restrict__ bhh,            // [3072]
           const int* __restrict__ lengths,          // [32]
           const float* __restrict__ h0,             // dec: [32,1024]
           float* __restrict__ hT,                   // enc: [32,1024]
           unsigned short* __restrict__ ys,          // dec: [B,T,1024] bf16
           unsigned short* __restrict__ hbuf,        // [2][32][1024] bf16
           unsigned* __restrict__ bar)
{
  const int wg = blockIdx.x;
  const int U0 = wg * 16;
  const int tid = threadIdx.x;
  const int lane = tid & 63, wv = tid >> 6;
  const int mt = wv & 1, g = wv >> 1;

  __shared__ float gh_lds[32][48];
  __shared__ float h_master[32][16];
  __shared__ float bhh_s[48];
  __shared__ int len_s[32];

  if (tid < 32) len_s[tid] = lengths[tid];
  if (tid < 48) bhh_s[tid] = bhh[(tid >> 4) * 1024 + U0 + (tid & 15)];

  // resident B fragments: rows g*1024 + U0 + (lane&15), k = kc*32 + (lane>>4)*8 .. +7
  bf16x8 bfrag[32];
  {
    const unsigned short* wrow = Whhb + (size_t)(g * 1024 + U0 + (lane & 15)) * 1024 + ((lane >> 4) * 8);
#pragma unroll
    for (int kc = 0; kc < 32; ++kc)
      bfrag[kc] = *(const bf16x8*)(wrow + kc * 32);
  }

  // init h, hbuf[0]
  for (int p = tid; p < 512; p += 384) {
    int b = p >> 4, u = p & 15;
    float h = IS_DEC ? h0[b * 1024 + U0 + u] : 0.f;
    h_master[b][u] = h;
    hbuf[b * 1024 + U0 + u] = f2bf(h);
  }
  unsigned phase = 1;
  gbar(bar, phase * 64); ++phase;

  for (int t = 0; t < T_; ++t) {
    const unsigned short* hb = hbuf + (t & 1) * (32 * 1024);
    f32x4 a0 = {0.f, 0.f, 0.f, 0.f}, a1 = {0.f, 0.f, 0.f, 0.f};
    const unsigned short* arow = hb + (size_t)(mt * 16 + (lane & 15)) * 1024 + ((lane >> 4) * 8);
#pragma unroll
    for (int kc = 0; kc < 32; kc += 2) {
      bf16x8 f0 = *(const bf16x8*)(arow + kc * 32);
      bf16x8 f1 = *(const bf16x8*)(arow + kc * 32 + 32);
      a0 = __builtin_amdgcn_mfma_f32_16x16x32_bf16(f0, bfrag[kc], a0, 0, 0, 0);
      a1 = __builtin_amdgcn_mfma_f32_16x16x32_bf16(f1, bfrag[kc + 1], a1, 0, 0, 0);
    }
#pragma unroll
    for (int q = 0; q < 4; ++q)
      gh_lds[mt * 16 + (lane >> 4) * 4 + q][g * 16 + (lane & 15)] = a0[q] + a1[q];
    __syncthreads();

    if (tid < 256) {
      int b = tid >> 3, u2 = tid & 7;
      int valid = t < len_s[b];
      const unsigned short* gib = gi + (size_t)(b * T_ + t) * G3 + U0 + u2 * 2;
      unsigned vr = *(const unsigned*)(gib);
      unsigned vz = *(const unsigned*)(gib + 1024);
      unsigned vn = *(const unsigned*)(gib + 2048);
      unsigned hw = 0, yw = 0;
#pragma unroll
      for (int j = 0; j < 2; ++j) {
        int u = u2 * 2 + j;
        float ir  = bf2f((unsigned short)(j ? (vr >> 16) : (vr & 0xffff)));
        float iz  = bf2f((unsigned short)(j ? (vz >> 16) : (vz & 0xffff)));
        float in_ = bf2f((unsigned short)(j ? (vn >> 16) : (vn & 0xffff)));
        float gr = gh_lds[b][u]      + bhh_s[u];
        float gz = gh_lds[b][16 + u] + bhh_s[16 + u];
        float gn = gh_lds[b][32 + u] + bhh_s[32 + u];
        float rr = 1.f / (1.f + expf(-(ir + gr)));
        float zz = 1.f / (1.f + expf(-(iz + gz)));
        float nn = tanhf(in_ + rr * gn);
        float hp = h_master[b][u];
        float hn = valid ? ((1.f - zz) * nn + zz * hp) : hp;
        h_master[b][u] = hn;
        unsigned short hb16 = f2bf(hn);
        hw |= ((unsigned)hb16) << (16 * j);
        if (IS_DEC) { unsigned short yb = valid ? hb16 : (unsigned short)0; yw |= ((unsigned)yb) << (16 * j); }
      }
      unsigned* hnext = (unsigned*)(hbuf + ((t + 1) & 1) * (32 * 1024));
      hnext[(b * 1024 + U0 + u2 * 2) >> 1] = hw;
      if (IS_DEC) ((unsigned*)ys)[((size_t)(b * T_ + t) * 1024 + U0 + u2 * 2) >> 1] = yw;
    }
    gbar(bar, phase * 64); ++phase;
  }

  if (!IS_DEC && tid < 256) {
    int b = tid >> 3, u2 = tid & 7;
    hT[b * 1024 + U0 + u2 * 2]     = h_master[b][u2 * 2];
    hT[b * 1024 + U0 + u2 * 2 + 1] = h_master[b][u2 * 2 + 1];
  }
}

// ---------------- VAE middle: mean/logv/z (sorted order) + dec_h0 ----------------
__global__ __launch_bounds__(256)
void k_mid(const float* __restrict__ h_enc,
           const float* __restrict__ Wm, const float* __restrict__ bm,
           const float* __restrict__ Wv, const float* __restrict__ bv,
           const float* __restrict__ Wl, const float* __restrict__ bl,
           const float* __restrict__ eps, const int* __restrict__ lengths,
           float* __restrict__ out_mean, float* __restrict__ out_logv,
           float* __restrict__ out_z, float* __restrict__ dec_h0)
{
  const int b = blockIdx.x;
  const int tid = threadIdx.x;
  __shared__ float h_s[1024];
  __shared__ float mean_s[128], logv_s[128], z_s[128];
  __shared__ int pos_s;
  for (int i = tid; i < 1024; i += 256) h_s[i] = h_enc[b * 1024 + i];
  if (tid == 0) {
    int lb = lengths[b], r = 0;
    for (int j = 0; j < 32; ++j) {
      int lj = lengths[j];
      r += (lj > lb) || (lj == lb && j < b);  // stable descending rank
    }
    pos_s = r;
  }
  __syncthreads();
  {
    const float* wrow = (tid < 128) ? (Wm + tid * 1024) : (Wv + (tid - 128) * 1024);
    float s = 0.f;
    for (int k = 0; k < 1024; ++k) s += h_s[k] * wrow[k];
    s += (tid < 128) ? bm[tid] : bv[tid - 128];
    if (tid < 128) mean_s[tid] = s; else logv_s[tid - 128] = s;
  }
  __syncthreads();
  int pos = pos_s;
  if (tid < 128) {
    float zv = eps[pos * 128 + tid] * expf(0.5f * logv_s[tid]) + mean_s[tid];
    z_s[tid] = zv;
    out_mean[pos * 128 + tid] = mean_s[tid];
    out_logv[pos * 128 + tid] = logv_s[tid];
    out_z[pos * 128 + tid]    = zv;
  }
  __syncthreads();
  for (int h = tid; h < 1024; h += 256) {
    float s = bl[h];
    const float* w = Wl + h * 128;
    for (int k = 0; k < 128; ++k) s += z_s[k] * w[k];
    dec_h0[b * 1024 + h] = s;
  }
}

// ---------------- host ----------------
extern "C" void kernel_launch(void* const* d_in, const int* in_sizes, int n_in,
                              void* d_out, int out_size, void* d_ws, size_t ws_size,
                              hipStream_t stream)
{
  const float* x     = (const float*)d_in[0];
  const float* eps   = (const float*)d_in[1];
  const float* W1    = (const float*)d_in[2];
  const float* b1    = (const float*)d_in[3];
  const float* W2    = (const float*)d_in[4];
  const float* b2    = (const float*)d_in[5];
  const float* Wih_e = (const float*)d_in[6];
  const float* Whh_e = (const float*)d_in[7];
  const float* bih_e = (const float*)d_in[8];
  const float* bhh_e = (const float*)d_in[9];
  const float* Wih_d = (const float*)d_in[10];
  const float* Whh_d = (const float*)d_in[11];
  const float* bih_d = (const float*)d_in[12];
  const float* bhh_d = (const float*)d_in[13];
  const float* Wm    = (const float*)d_in[14];
  const float* bm    = (const float*)d_in[15];
  const float* Wv    = (const float*)d_in[16];
  const float* bv    = (const float*)d_in[17];
  const float* Wl    = (const float*)d_in[18];
  const float* bl    = (const float*)d_in[19];
  const float* Wo    = (const float*)d_in[20];
  const float* bo    = (const float*)d_in[21];
  const int* lengths = (const int*)d_in[22];

  char* ws = (char*)d_ws;
  unsigned short* xb    = (unsigned short*)(ws + 0);          // 32MB; reused as ys
  unsigned short* proj  = (unsigned short*)(ws + 33554432);   // 32MB
  unsigned short* gi    = (unsigned short*)(ws + 67108864);   // 100.66MB (P1 aliases head)
  unsigned short* W1b   = (unsigned short*)(ws + 167772160);
  unsigned short* W2b   = (unsigned short*)(ws + 169869312);
  unsigned short* Wiheb = (unsigned short*)(ws + 171966464);
  unsigned short* Wihdb = (unsigned short*)(ws + 178257920);
  unsigned short* Whheb = (unsigned short*)(ws + 184549376);
  unsigned short* Whhdb = (unsigned short*)(ws + 190840832);
  unsigned short* Wob   = (unsigned short*)(ws + 197132288);
  unsigned short* hbuf  = (unsigned short*)(ws + 199229440);  // 128KB
  float* h_enc          = (float*)(ws + 199360512);           // 128KB
  float* dec_h0         = (float*)(ws + 199491584);           // 128KB
  unsigned* bars        = (unsigned*)(ws + 199622656);        // 512B

  float* out_x    = (float*)d_out;
  float* out_ol   = (float*)d_out + 16777216;
  float* out_mean = (float*)d_out + 2 * 16777216;
  float* out_logv = out_mean + 4096;
  float* out_z    = out_logv + 4096;

  hipMemcpyAsync(out_x, x, (size_t)16777216 * 4, hipMemcpyDeviceToDevice, stream);
  hipMemsetAsync(bars, 0, 512, stream);

  auto cv = [&](const float* s, unsigned short* d, int n) {
    k_f2bf<<<dim3((n / 4 + 255) / 256), dim3(256), 0, stream>>>(s, d, n);
  };
  cv(x, xb, BT * E_);
  cv(W1, W1b, H_ * E_);
  cv(W2, W2b, H_ * H_);
  cv(Wih_e, Wiheb, G3 * H_);
  cv(Wih_d, Wihdb, G3 * H_);
  cv(Whh_e, Whheb, G3 * H_);
  cv(Whh_d, Whhdb, G3 * H_);
  cv(Wo, Wob, E_ * H_);

  unsigned short* P1 = gi;  // alias: P1 dead before gi written
  // P1 = relu(x @ W1^T + b1)
  k_gemm<0, 1><<<dim3(BT / 128, H_ / 128), 256, 0, stream>>>(xb, W1b, b1, P1, BT, H_, E_);
  // proj = P1 @ W2^T + b2
  k_gemm<0, 0><<<dim3(BT / 128, H_ / 128), 256, 0, stream>>>(P1, W2b, b2, proj, BT, H_, H_);
  // gi_e = proj @ Wih_e^T + bih_e
  k_gemm<0, 0><<<dim3(BT / 128, G3 / 128), 256, 0, stream>>>(proj, Wiheb, bih_e, gi, BT, G3, H_);
  // encoder GRU
  k_gru<0><<<64, 384, 0, stream>>>(gi, Whheb, bhh_e, lengths, nullptr, h_enc, nullptr, hbuf, bars);
  // VAE middle
  k_mid<<<32, 256, 0, stream>>>(h_enc, Wm, bm, Wv, bv, Wl, bl, eps, lengths,
                                out_mean, out_logv, out_z, dec_h0);
  // gi_d = proj @ Wih_d^T + bih_d  (reuse gi buffer)
  k_gemm<0, 0><<<dim3(BT / 128, G3 / 128), 256, 0, stream>>>(proj, Wihdb, bih_d, gi, BT, G3, H_);
  // decoder GRU (ys into xb region)
  unsigned short* ys = xb;
  k_gru<1><<<64, 384, 0, stream>>>(gi, Whhdb, bhh_d, lengths, dec_h0, nullptr, ys, hbuf, bars + 64);
  // outputs_layer = ys @ Wo^T + bo (fp32 straight into d_out)
  k_gemm<1, 0><<<dim3(BT / 128, E_ / 128), 256, 0, stream>>>(ys, Wob, bo, out_ol, BT, E_, H_);
}